// Round 3
// baseline (1020.746 us; speedup 1.0000x reference)
//
#include <hip/hip_runtime.h>
#include <hip/hip_bf16.h>
#include <stdint.h>

#define BATCH 256
#define PFD 128
#define T1 129
#define NPAIRS 1089      // 33*33
#define TSTR 132         // t-table row stride (floats)
#define BKSTR 72         // b_lds row stride (bf16), 144B: balanced banks
#define CHUNK 16

typedef short bf16x8 __attribute__((ext_vector_type(8)));
typedef float f32x4 __attribute__((ext_vector_type(4)));

static __device__ __forceinline__ unsigned bits_of(float f){ union{float f;unsigned u;}x;x.f=f;return x.u; }
static __device__ __forceinline__ float float_of(unsigned u){ union{float f;unsigned u;}x;x.u=u;return x.f; }
static __device__ __forceinline__ unsigned pk_bf16(float a, float b){
  union { __hip_bfloat162 h; unsigned u; } c;
  c.h = __float22bfloat162_rn(make_float2(a, b));
  return c.u;
}

// ---------------- Kernel 1 ----------------
// h1-partials via G-factorization: for each (ia,iv) pair p,
//   contrib[m,n] = av[m,p] * ( sum_it t[m,it] * W1[p,it,n] )
// t hi/lo fragments built once (exact split); G = MFMA(t_hi)+MFMA(t_lo);
// acc += av * G in fp32. it=128 handled as per-chunk remainder tile.
__global__ __launch_bounds__(512, 2) void tfn_k1(
    const float* __restrict__ audio, const float* __restrict__ video,
    const float* __restrict__ text, const float* __restrict__ W1,
    unsigned short* __restrict__ part, int S) {
  __shared__ __align__(16) char uni[BATCH * TSTR * 4];   // 135168B: t-table, then W1 dbuf
  __shared__ __align__(16) float av_lds[BATCH * CHUNK];  // 16384B
  __shared__ float t128_lds[BATCH];                      // 1024B
  float* t_lds = (float*)uni;
  short* b_lds = (short*)uni;            // [2][PFD*BKSTR] bf16 after t-phase

  const int tid = threadIdx.x;
  const int bk = blockIdx.x;
  const int npb = NPAIRS / S, rem0 = NPAIRS % S;
  const int p0 = bk * npb + (bk < rem0 ? bk : rem0);
  const int np = npb + (bk < rem0 ? 1 : 0);

  // phase 1: stage t fp32 (col0 = 1, cols 1..128 = text)
  for (int i = tid; i < BATCH * 32; i += 512) {
    int m = i >> 5, g = (i & 31) << 2;
    float4 v = *(const float4*)&text[m * 128 + g];
    float* dst = &t_lds[m * TSTR + 1 + g];
    dst[0] = v.x; dst[1] = v.y; dst[2] = v.z; dst[3] = v.w;
  }
  if (tid < BATCH) { t_lds[tid * TSTR] = 1.0f; t128_lds[tid] = text[tid * 128 + 127]; }
  __syncthreads();

  const int wave = tid >> 6, lane = tid & 63;
  const int l15 = lane & 15, quad = lane >> 4;
  const int sn = tid & 127, skg = tid >> 7;

  // persistent t-fragments (hi = trunc, lo = RNE(resid); split exact to ~2^-17)
  bf16x8 thi[2][4], tlo[2][4];
  #pragma unroll
  for (int mt = 0; mt < 2; ++mt) {
    const int m = wave * 32 + mt * 16 + l15;
    #pragma unroll
    for (int ks = 0; ks < 4; ++ks) {
      const float4 ta = *(const float4*)&t_lds[m * TSTR + ks * 32 + quad * 8];
      const float4 tb = *(const float4*)&t_lds[m * TSTR + ks * 32 + quad * 8 + 4];
      const float f[8] = {ta.x, ta.y, ta.z, ta.w, tb.x, tb.y, tb.z, tb.w};
      union { bf16x8 v; unsigned u[4]; } H, L;
      #pragma unroll
      for (int d = 0; d < 4; ++d) {
        unsigned b0 = bits_of(f[2 * d]), b1 = bits_of(f[2 * d + 1]);
        H.u[d] = (b1 & 0xFFFF0000u) | (b0 >> 16);
        L.u[d] = pk_bf16(f[2 * d]     - float_of(b0 & 0xFFFF0000u),
                         f[2 * d + 1] - float_of(b1 & 0xFFFF0000u));
      }
      thi[mt][ks] = H.v; tlo[mt][ks] = L.v;
    }
  }

  f32x4 acc[2][8];
  #pragma unroll
  for (int a = 0; a < 2; ++a)
    #pragma unroll
    for (int b = 0; b < 8; ++b) acc[a][b] = f32x4{0.f, 0.f, 0.f, 0.f};

  float pf[16];
  float rv[8];

  for (int c0 = 0; c0 < np; c0 += CHUNK) {
    const int nc = (np - c0) < CHUNK ? (np - c0) : CHUNK;
    const int pbase = p0 + c0;
    __syncthreads();   // t-frag reads / prev chunk's LDS readers done
    if (tid < BATCH) {
      const int m = tid;
      for (int j = 0; j < nc; ++j) {
        int p = pbase + j;
        int ia = p / 33, iv = p - ia * 33;
        float a = (ia == 0) ? 1.0f : audio[m * 32 + ia - 1];
        float v = (iv == 0) ? 1.0f : video[m * 32 + iv - 1];
        av_lds[m * CHUNK + j] = a * v;
      }
    }
    // prefetch remainder row (it=128) for this chunk
    #pragma unroll
    for (int j = 0; j < 8; ++j) {
      int kk = skg * 8 + j;
      rv[j] = (kk < nc) ? W1[((long)(pbase + kk) * T1 + 128) * PFD + sn] : 0.0f;
    }
    // prefetch tile 0
    {
      const long rowbase = (long)pbase * T1;
      #pragma unroll
      for (int g = 0; g < 2; ++g)
        #pragma unroll
        for (int j = 0; j < 8; ++j)
          pf[g * 8 + j] = W1[(rowbase + g * 32 + skg * 8 + j) * PFD + sn];
    }
    const int ntiles = nc * 2;
    f32x4 G[2][8];
    for (int s = 0; s < ntiles; ++s) {
      const int boff = (s & 1) * (PFD * BKSTR);
      {
        union { bf16x8 v; unsigned u[4]; } w0, w1;
        #pragma unroll
        for (int d = 0; d < 4; ++d) {
          w0.u[d] = pk_bf16(pf[2 * d],     pf[2 * d + 1]);
          w1.u[d] = pk_bf16(pf[8 + 2 * d], pf[8 + 2 * d + 1]);
        }
        *(bf16x8*)&b_lds[boff + sn * BKSTR + skg * 8]      = w0.v;
        *(bf16x8*)&b_lds[boff + sn * BKSTR + 32 + skg * 8] = w1.v;
      }
      if (s + 1 < ntiles) {    // next-tile prefetch; in flight across the barrier
        const int jp1 = (s + 1) >> 1, h1 = (s + 1) & 1;
        const long rowbase = (long)(pbase + jp1) * T1 + h1 * 64;
        #pragma unroll
        for (int g = 0; g < 2; ++g)
          #pragma unroll
          for (int j = 0; j < 8; ++j)
            pf[g * 8 + j] = W1[(rowbase + g * 32 + skg * 8 + j) * PFD + sn];
      }
      __syncthreads();
      const int jp = s >> 1;
      if ((s & 1) == 0) {
        #pragma unroll
        for (int a = 0; a < 2; ++a)
          #pragma unroll
          for (int b = 0; b < 8; ++b) G[a][b] = f32x4{0.f, 0.f, 0.f, 0.f};
      }
      #pragma unroll
      for (int ks2 = 0; ks2 < 2; ++ks2) {
        const int ks = (s & 1) * 2 + ks2;
        #pragma unroll
        for (int nt = 0; nt < 8; ++nt) {
          bf16x8 bf = *(const bf16x8*)&b_lds[boff + (nt * 16 + l15) * BKSTR + ks2 * 32 + quad * 8];
          G[0][nt] = __builtin_amdgcn_mfma_f32_16x16x32_bf16(thi[0][ks], bf, G[0][nt], 0, 0, 0);
          G[0][nt] = __builtin_amdgcn_mfma_f32_16x16x32_bf16(tlo[0][ks], bf, G[0][nt], 0, 0, 0);
          G[1][nt] = __builtin_amdgcn_mfma_f32_16x16x32_bf16(thi[1][ks], bf, G[1][nt], 0, 0, 0);
          G[1][nt] = __builtin_amdgcn_mfma_f32_16x16x32_bf16(tlo[1][ks], bf, G[1][nt], 0, 0, 0);
        }
      }
      if (s & 1) {   // pair complete: acc += av * G (full-fp32 scale)
        float avv[2][4];
        #pragma unroll
        for (int mt = 0; mt < 2; ++mt)
          #pragma unroll
          for (int r = 0; r < 4; ++r)
            avv[mt][r] = av_lds[(wave * 32 + mt * 16 + quad * 4 + r) * CHUNK + jp];
        #pragma unroll
        for (int mt = 0; mt < 2; ++mt)
          #pragma unroll
          for (int nt = 0; nt < 8; ++nt)
            #pragma unroll
            for (int r = 0; r < 4; ++r)
              acc[mt][nt][r] += avv[mt][r] * G[mt][nt][r];
      }
    }
    // remainder tile: it=128, k-slot = pair index (av*t128 product split)
    {
      const int boff = (ntiles & 1) * (PFD * BKSTR);
      union { bf16x8 v; unsigned u[4]; } w;
      #pragma unroll
      for (int d = 0; d < 4; ++d) w.u[d] = pk_bf16(rv[2 * d], rv[2 * d + 1]);
      *(bf16x8*)&b_lds[boff + sn * BKSTR + skg * 8] = w.v;
      __syncthreads();
      bf16x8 ahi[2], alo[2];
      #pragma unroll
      for (int mt = 0; mt < 2; ++mt) {
        const int m = wave * 32 + mt * 16 + l15;
        const float t128 = t128_lds[m];
        float f[8];
        #pragma unroll
        for (int j = 0; j < 8; ++j) {
          int kk = quad * 8 + j;
          f[j] = (kk < nc) ? av_lds[m * CHUNK + kk] * t128 : 0.0f;
        }
        union { bf16x8 v; unsigned u[4]; } H, L;
        #pragma unroll
        for (int d = 0; d < 4; ++d) {
          unsigned b0 = bits_of(f[2 * d]), b1 = bits_of(f[2 * d + 1]);
          H.u[d] = (b1 & 0xFFFF0000u) | (b0 >> 16);
          L.u[d] = pk_bf16(f[2 * d]     - float_of(b0 & 0xFFFF0000u),
                           f[2 * d + 1] - float_of(b1 & 0xFFFF0000u));
        }
        ahi[mt] = H.v; alo[mt] = L.v;
      }
      #pragma unroll
      for (int nt = 0; nt < 8; ++nt) {
        bf16x8 bf = *(const bf16x8*)&b_lds[boff + (nt * 16 + l15) * BKSTR + quad * 8];
        acc[0][nt] = __builtin_amdgcn_mfma_f32_16x16x32_bf16(ahi[0], bf, acc[0][nt], 0, 0, 0);
        acc[0][nt] = __builtin_amdgcn_mfma_f32_16x16x32_bf16(alo[0], bf, acc[0][nt], 0, 0, 0);
        acc[1][nt] = __builtin_amdgcn_mfma_f32_16x16x32_bf16(ahi[1], bf, acc[1][nt], 0, 0, 0);
        acc[1][nt] = __builtin_amdgcn_mfma_f32_16x16x32_bf16(alo[1], bf, acc[1][nt], 0, 0, 0);
      }
    }
  }

  // writeback: bf16, m-major [m][S][phys_n]; phys n = l15*8 + nt (k2 un-swizzles)
  #pragma unroll
  for (int mt = 0; mt < 2; ++mt)
    #pragma unroll
    for (int r = 0; r < 4; ++r) {
      const int m = wave * 32 + mt * 16 + quad * 4 + r;
      union { bf16x8 v; unsigned u[4]; } w;
      #pragma unroll
      for (int d = 0; d < 4; ++d) w.u[d] = pk_bf16(acc[mt][2 * d][r], acc[mt][2 * d + 1][r]);
      *(bf16x8*)&part[((size_t)m * S + bk) * PFD + l15 * 8] = w.v;
    }
}

// ---------------- Kernel 2: contiguous reduce + bias/relu + layers 2,3 ----------------
__global__ __launch_bounds__(256) void tfn_k2(
    const unsigned short* __restrict__ part, const float* __restrict__ b1,
    const float* __restrict__ W2, const float* __restrict__ b2,
    const float* __restrict__ W3, const float* __restrict__ b3,
    float* __restrict__ out, int S) {
  __shared__ float sred[256 * 4];
  __shared__ float h1s[PFD];
  __shared__ float a2s[256];
  __shared__ float red[2];
  const int m = blockIdx.x, tid = threadIdx.x;
  const int g = tid & 31, q = tid >> 5;
  const unsigned short* base = part + (size_t)m * S * PFD;
  float s0 = 0, s1 = 0, s2 = 0, s3 = 0;
  for (int bkk = q; bkk < S; bkk += 8) {
    uint2 v = *(const uint2*)&base[(size_t)bkk * PFD + g * 4];
    s0 += float_of(v.x << 16);
    s1 += float_of(v.x & 0xFFFF0000u);
    s2 += float_of(v.y << 16);
    s3 += float_of(v.y & 0xFFFF0000u);
  }
  sred[tid * 4 + 0] = s0; sred[tid * 4 + 1] = s1;
  sred[tid * 4 + 2] = s2; sred[tid * 4 + 3] = s3;
  __syncthreads();
  if (tid < PFD) {
    const int p = tid;
    float h = 0;
    #pragma unroll
    for (int bl = 0; bl < 8; ++bl) h += sred[(bl * 32 + (p >> 2)) * 4 + (p & 3)];
    const int n = (p & 7) * 16 + (p >> 3);   // un-swizzle phys -> logical
    h1s[n] = fmaxf(h + b1[n], 0.0f);
  }
  __syncthreads();
  const int n = tid & 127, half = tid >> 7;
  float a2 = 0.0f;
  const int k0 = half * 64;
  #pragma unroll 8
  for (int k = 0; k < 64; ++k) a2 += h1s[k0 + k] * W2[(k0 + k) * PFD + n];
  a2s[tid] = a2;
  __syncthreads();
  if (half == 0) {
    float h2 = fmaxf(a2s[n] + a2s[n + 128] + b2[n], 0.0f);
    float pr = h2 * W3[n];
    #pragma unroll
    for (int off = 32; off > 0; off >>= 1) pr += __shfl_down(pr, off);
    if ((tid & 63) == 0) red[tid >> 6] = pr;
  }
  __syncthreads();
  if (tid == 0) out[m] = red[0] + red[1] + b3[0];
}

extern "C" void kernel_launch(void* const* d_in, const int* in_sizes, int n_in,
                              void* d_out, int out_size, void* d_ws, size_t ws_size,
                              hipStream_t stream) {
  const float* audio = (const float*)d_in[0];
  const float* video = (const float*)d_in[1];
  const float* text  = (const float*)d_in[2];
  const float* W1 = (const float*)d_in[3];
  const float* b1 = (const float*)d_in[4];
  const float* W2 = (const float*)d_in[5];
  const float* b2 = (const float*)d_in[6];
  const float* W3 = (const float*)d_in[7];
  const float* b3 = (const float*)d_in[8];
  unsigned short* part = (unsigned short*)d_ws;

  const size_t slab = (size_t)BATCH * PFD * sizeof(unsigned short);  // 64 KB
  int S = (int)(ws_size / slab);
  if (S > 256) S = 256;
  if (S < 1) S = 1;

  tfn_k1<<<S, 512, 0, stream>>>(audio, video, text, W1, part, S);
  tfn_k2<<<BATCH, 256, 0, stream>>>(part, b1, W2, b2, W3, b3, (float*)d_out, S);
}

// Round 4
// 146.146 us; speedup vs baseline: 6.9844x; 6.9844x over previous
//
#include <hip/hip_runtime.h>
#include <hip/hip_bf16.h>
#include <stdint.h>

#define BATCH 256
#define PFD 128
#define T1 129
#define NPAIRS 1089      // 33*33
#define BKSTR 72         // b_lds row stride (bf16 shorts); 36 dwords -> 8cyc b128 optimum
#define CHUNK 8

typedef short bf16x8 __attribute__((ext_vector_type(8)));
typedef float f32x4 __attribute__((ext_vector_type(4)));

static __device__ __forceinline__ unsigned bits_of(float f){ union{float f;unsigned u;}x;x.f=f;return x.u; }
static __device__ __forceinline__ float float_of(unsigned u){ union{float f;unsigned u;}x;x.u=u;return x.f; }
static __device__ __forceinline__ unsigned pk_bf16(float a, float b){
  union { __hip_bfloat162 h; unsigned u; } c;
  c.h = __float22bfloat162_rn(make_float2(a, b));
  return c.u;
}

// ---------------- Kernel 1: split-K fused trilinear GEMM ----------------
// Block bk owns ~4-5 (ia,iv) pairs. Per pair p: acc[m,n] += sum_it bf16(av[m,p]*t[m,it]) * bf16(W1[p,it,n])
// t held in VGPRs (A-layout, fp32), av folded per pair. W1 staged via depth-2
// register pipeline into LDS double buffer. No t-table in LDS.
__global__ __launch_bounds__(512, 2) void tfn_k1(
    const float* __restrict__ audio, const float* __restrict__ video,
    const float* __restrict__ text, const float* __restrict__ W1,
    unsigned short* __restrict__ part, int S) {
  __shared__ __align__(16) short b_lds[2][PFD * BKSTR];  // 2 x 18432 B
  __shared__ __align__(16) float av_lds[BATCH * CHUNK];  // 8192 B

  const int tid = threadIdx.x;
  const int bk = blockIdx.x;
  const int npb = NPAIRS / S, rem0 = NPAIRS % S;
  const int p0 = bk * npb + (bk < rem0 ? bk : rem0);
  const int np = npb + (bk < rem0 ? 1 : 0);

  const int wave = tid >> 6, lane = tid & 63;
  const int l15 = lane & 15, quad = lane >> 4;
  const int sn = tid & 127, skg = tid >> 7;

  // t fragments in registers, fp32, MFMA A-layout: treg[mt][ks*8+j] = t(m, ks*32+quad*8+j)
  float treg[2][32];
  float t128r[2];
  #pragma unroll
  for (int mt = 0; mt < 2; ++mt) {
    const int m = wave * 32 + mt * 16 + l15;
    t128r[mt] = text[m * 128 + 127];
    #pragma unroll
    for (int ks = 0; ks < 4; ++ks)
      #pragma unroll
      for (int j = 0; j < 8; ++j) {
        const int it = ks * 32 + quad * 8 + j;
        treg[mt][ks * 8 + j] = (it == 0) ? 1.0f : text[m * 128 + it - 1];
      }
  }

  f32x4 acc[2][8];
  #pragma unroll
  for (int a = 0; a < 2; ++a)
    #pragma unroll
    for (int b = 0; b < 8; ++b) acc[a][b] = f32x4{0.f, 0.f, 0.f, 0.f};

  float pf0[16], pf1[16], rv[8];

  for (int c0 = 0; c0 < np; c0 += CHUNK) {
    const int nc = (np - c0) < CHUNK ? (np - c0) : CHUNK;
    const int pbase = p0 + c0;
    __syncthreads();   // prev chunk fully done
    if (tid < BATCH) {
      const int m = tid;
      for (int j = 0; j < nc; ++j) {
        int p = pbase + j;
        int ia = p / 33, iv = p - ia * 33;
        float a = (ia == 0) ? 1.0f : audio[m * 32 + ia - 1];
        float v = (iv == 0) ? 1.0f : video[m * 32 + iv - 1];
        av_lds[m * CHUNK + j] = a * v;
      }
    }
    // remainder row (it=128) prefetch — in flight across whole chunk
    #pragma unroll
    for (int j = 0; j < 8; ++j) {
      int kk = skg * 8 + j;
      rv[j] = (kk < nc) ? W1[((long)(pbase + kk) * T1 + 128) * PFD + sn] : 0.0f;
    }
    // prime pipeline: tiles 0 (pair 0, lo half) and 1 (pair 0, hi half)
    {
      const long rb = (long)pbase * T1;
      #pragma unroll
      for (int g = 0; g < 2; ++g)
        #pragma unroll
        for (int j = 0; j < 8; ++j) {
          pf0[g * 8 + j] = W1[(rb + g * 32 + skg * 8 + j) * PFD + sn];
          pf1[g * 8 + j] = W1[(rb + 64 + g * 32 + skg * 8 + j) * PFD + sn];
        }
    }
    for (int sp = 0; sp < nc; ++sp) {
      // per-pair av (A-layout row: m = ...*16 + l15)
      float avm[2];
      // ---- tile 2*sp (k-half 0) -> buf 0, regs pf0 ----
      __syncthreads();   // buf0 readers (tile 2sp-2) done; av_lds ready (sp=0)
      avm[0] = av_lds[(wave * 32 + l15) * CHUNK + sp];
      avm[1] = av_lds[(wave * 32 + 16 + l15) * CHUNK + sp];
      {
        union { bf16x8 v; unsigned u[4]; } w0, w1;
        #pragma unroll
        for (int d = 0; d < 4; ++d) {
          w0.u[d] = pk_bf16(pf0[2 * d], pf0[2 * d + 1]);
          w1.u[d] = pk_bf16(pf0[8 + 2 * d], pf0[8 + 2 * d + 1]);
        }
        *(bf16x8*)&b_lds[0][sn * BKSTR + skg * 8] = w0.v;
        *(bf16x8*)&b_lds[0][sn * BKSTR + 32 + skg * 8] = w1.v;
      }
      if (sp + 1 < nc) {   // prefetch pair sp+1, lo half (tile 2sp+2)
        const long rb = (long)(pbase + sp + 1) * T1;
        #pragma unroll
        for (int g = 0; g < 2; ++g)
          #pragma unroll
          for (int j = 0; j < 8; ++j)
            pf0[g * 8 + j] = W1[(rb + g * 32 + skg * 8 + j) * PFD + sn];
      }
      __syncthreads();   // buf0 staged
      #pragma unroll
      for (int ks = 0; ks < 2; ++ks) {
        bf16x8 A0, A1;
        {
          union { bf16x8 v; unsigned u[4]; } c0u, c1u;
          #pragma unroll
          for (int d = 0; d < 4; ++d) {
            c0u.u[d] = pk_bf16(avm[0] * treg[0][ks * 8 + 2 * d], avm[0] * treg[0][ks * 8 + 2 * d + 1]);
            c1u.u[d] = pk_bf16(avm[1] * treg[1][ks * 8 + 2 * d], avm[1] * treg[1][ks * 8 + 2 * d + 1]);
          }
          A0 = c0u.v; A1 = c1u.v;
        }
        #pragma unroll
        for (int nt = 0; nt < 8; ++nt) {
          bf16x8 bf = *(const bf16x8*)&b_lds[0][(nt * 16 + l15) * BKSTR + ks * 32 + quad * 8];
          acc[0][nt] = __builtin_amdgcn_mfma_f32_16x16x32_bf16(A0, bf, acc[0][nt], 0, 0, 0);
          acc[1][nt] = __builtin_amdgcn_mfma_f32_16x16x32_bf16(A1, bf, acc[1][nt], 0, 0, 0);
        }
      }
      // ---- tile 2*sp+1 (k-half 1) -> buf 1, regs pf1 ----
      __syncthreads();   // buf1 readers (tile 2sp-1) done
      {
        union { bf16x8 v; unsigned u[4]; } w0, w1;
        #pragma unroll
        for (int d = 0; d < 4; ++d) {
          w0.u[d] = pk_bf16(pf1[2 * d], pf1[2 * d + 1]);
          w1.u[d] = pk_bf16(pf1[8 + 2 * d], pf1[8 + 2 * d + 1]);
        }
        *(bf16x8*)&b_lds[1][sn * BKSTR + skg * 8] = w0.v;
        *(bf16x8*)&b_lds[1][sn * BKSTR + 32 + skg * 8] = w1.v;
      }
      if (sp + 1 < nc) {   // prefetch pair sp+1, hi half (tile 2sp+3)
        const long rb = (long)(pbase + sp + 1) * T1 + 64;
        #pragma unroll
        for (int g = 0; g < 2; ++g)
          #pragma unroll
          for (int j = 0; j < 8; ++j)
            pf1[g * 8 + j] = W1[(rb + g * 32 + skg * 8 + j) * PFD + sn];
      }
      __syncthreads();   // buf1 staged
      #pragma unroll
      for (int ks2 = 0; ks2 < 2; ++ks2) {
        const int ks = 2 + ks2;
        bf16x8 A0, A1;
        {
          union { bf16x8 v; unsigned u[4]; } c0u, c1u;
          #pragma unroll
          for (int d = 0; d < 4; ++d) {
            c0u.u[d] = pk_bf16(avm[0] * treg[0][ks * 8 + 2 * d], avm[0] * treg[0][ks * 8 + 2 * d + 1]);
            c1u.u[d] = pk_bf16(avm[1] * treg[1][ks * 8 + 2 * d], avm[1] * treg[1][ks * 8 + 2 * d + 1]);
          }
          A0 = c0u.v; A1 = c1u.v;
        }
        #pragma unroll
        for (int nt = 0; nt < 8; ++nt) {
          bf16x8 bf = *(const bf16x8*)&b_lds[1][(nt * 16 + l15) * BKSTR + ks2 * 32 + quad * 8];
          acc[0][nt] = __builtin_amdgcn_mfma_f32_16x16x32_bf16(A0, bf, acc[0][nt], 0, 0, 0);
          acc[1][nt] = __builtin_amdgcn_mfma_f32_16x16x32_bf16(A1, bf, acc[1][nt], 0, 0, 0);
        }
      }
    }
    // ---- remainder tile: it=128, k-slot = pair index ----
    __syncthreads();
    {
      union { bf16x8 v; unsigned u[4]; } w;
      #pragma unroll
      for (int d = 0; d < 4; ++d) w.u[d] = pk_bf16(rv[2 * d], rv[2 * d + 1]);
      *(bf16x8*)&b_lds[0][sn * BKSTR + skg * 8] = w.v;
    }
    __syncthreads();
    {
      bf16x8 A[2];
      #pragma unroll
      for (int mt = 0; mt < 2; ++mt) {
        const int m = wave * 32 + mt * 16 + l15;
        union { bf16x8 v; unsigned u[4]; } c;
        #pragma unroll
        for (int d = 0; d < 4; ++d) {
          int k0 = quad * 8 + 2 * d, k1 = k0 + 1;
          float f0 = (k0 < nc) ? av_lds[m * CHUNK + k0] * t128r[mt] : 0.0f;
          float f1 = (k1 < nc) ? av_lds[m * CHUNK + k1] * t128r[mt] : 0.0f;
          c.u[d] = pk_bf16(f0, f1);
        }
        A[mt] = c.v;
      }
      #pragma unroll
      for (int nt = 0; nt < 8; ++nt) {
        bf16x8 bf = *(const bf16x8*)&b_lds[0][(nt * 16 + l15) * BKSTR + quad * 8];
        acc[0][nt] = __builtin_amdgcn_mfma_f32_16x16x32_bf16(A[0], bf, acc[0][nt], 0, 0, 0);
        acc[1][nt] = __builtin_amdgcn_mfma_f32_16x16x32_bf16(A[1], bf, acc[1][nt], 0, 0, 0);
      }
    }
  }

  // writeback: bf16, m-major [m][S][phys_n], phys n = l15*8 + nt
  #pragma unroll
  for (int mt = 0; mt < 2; ++mt)
    #pragma unroll
    for (int r = 0; r < 4; ++r) {
      const int m = wave * 32 + mt * 16 + quad * 4 + r;
      union { bf16x8 v; unsigned u[4]; } w;
      #pragma unroll
      for (int d = 0; d < 4; ++d) w.u[d] = pk_bf16(acc[mt][2 * d][r], acc[mt][2 * d + 1][r]);
      *(bf16x8*)&part[((size_t)m * S + bk) * PFD + l15 * 8] = w.v;
    }
}

// ---------------- Kernel 2: contiguous reduce + bias/relu + layers 2,3 ----------------
__global__ __launch_bounds__(256) void tfn_k2(
    const unsigned short* __restrict__ part, const float* __restrict__ b1,
    const float* __restrict__ W2, const float* __restrict__ b2,
    const float* __restrict__ W3, const float* __restrict__ b3,
    float* __restrict__ out, int S) {
  __shared__ float sred[256 * 4];
  __shared__ float h1s[PFD];
  __shared__ float a2s[256];
  __shared__ float red[2];
  const int m = blockIdx.x, tid = threadIdx.x;
  const int g = tid & 31, q = tid >> 5;
  const unsigned short* base = part + (size_t)m * S * PFD;
  float s0 = 0, s1 = 0, s2 = 0, s3 = 0;
  for (int bkk = q; bkk < S; bkk += 8) {
    uint2 v = *(const uint2*)&base[(size_t)bkk * PFD + g * 4];
    s0 += float_of(v.x << 16);
    s1 += float_of(v.x & 0xFFFF0000u);
    s2 += float_of(v.y << 16);
    s3 += float_of(v.y & 0xFFFF0000u);
  }
  sred[tid * 4 + 0] = s0; sred[tid * 4 + 1] = s1;
  sred[tid * 4 + 2] = s2; sred[tid * 4 + 3] = s3;
  __syncthreads();
  if (tid < PFD) {
    const int p = tid;
    float h = 0;
    #pragma unroll
    for (int bl = 0; bl < 8; ++bl) h += sred[(bl * 32 + (p >> 2)) * 4 + (p & 3)];
    const int n = (p & 7) * 16 + (p >> 3);   // un-swizzle phys -> logical
    h1s[n] = fmaxf(h + b1[n], 0.0f);
  }
  __syncthreads();
  const int n = tid & 127, half = tid >> 7;
  float a2 = 0.0f;
  const int k0 = half * 64;
  #pragma unroll 8
  for (int k = 0; k < 64; ++k) a2 += h1s[k0 + k] * W2[(k0 + k) * PFD + n];
  a2s[tid] = a2;
  __syncthreads();
  if (half == 0) {
    float h2 = fmaxf(a2s[n] + a2s[n + 128] + b2[n], 0.0f);
    float pr = h2 * W3[n];
    #pragma unroll
    for (int off = 32; off > 0; off >>= 1) pr += __shfl_down(pr, off);
    if ((tid & 63) == 0) red[tid >> 6] = pr;
  }
  __syncthreads();
  if (tid == 0) out[m] = red[0] + red[1] + b3[0];
}

extern "C" void kernel_launch(void* const* d_in, const int* in_sizes, int n_in,
                              void* d_out, int out_size, void* d_ws, size_t ws_size,
                              hipStream_t stream) {
  const float* audio = (const float*)d_in[0];
  const float* video = (const float*)d_in[1];
  const float* text  = (const float*)d_in[2];
  const float* W1 = (const float*)d_in[3];
  const float* b1 = (const float*)d_in[4];
  const float* W2 = (const float*)d_in[5];
  const float* b2 = (const float*)d_in[6];
  const float* W3 = (const float*)d_in[7];
  const float* b3 = (const float*)d_in[8];
  unsigned short* part = (unsigned short*)d_ws;

  const size_t slab = (size_t)BATCH * PFD * sizeof(unsigned short);  // 64 KB
  int S = (int)(ws_size / slab);
  if (S > 256) S = 256;
  if (S < 1) S = 1;

  tfn_k1<<<S, 512, 0, stream>>>(audio, video, text, W1, part, S);
  tfn_k2<<<BATCH, 256, 0, stream>>>(part, b1, W2, b2, W3, b3, (float*)d_out, S);
}